// Round 1
// baseline (1155.986 us; speedup 1.0000x reference)
//
#include <hip/hip_runtime.h>
#include <hip/hip_bf16.h>
#include <math.h>

// ---------------------------------------------------------------------------
// GAT (3-layer, DGL-style) on MI355X.
// Phase 1: build CSR (incoming edges per dst) in workspace.
// Per layer: gemm_ft (ft = h@W, fused el/er) then gat_aggregate (online
// softmax over incoming edges, gather ft[src], no atomics).
// All fp32 (threshold 7.4e-4 absolute is too tight for bf16 storage).
// ---------------------------------------------------------------------------

#define WAVE 64

// ---------------- CSR build ----------------

__global__ __launch_bounds__(256) void count_deg(const int* __restrict__ dst,
                                                 int* __restrict__ cnt, int E) {
    int e = blockIdx.x * 256 + threadIdx.x;
    if (e < E) atomicAdd(&cnt[dst[e]], 1);
}

__global__ __launch_bounds__(256) void scan_block(const int* __restrict__ cnt,
                                                  int* __restrict__ rowptr,
                                                  int* __restrict__ bsum, int n) {
    __shared__ int sh[256];
    int i = blockIdx.x * 256 + threadIdx.x;
    int v = (i < n) ? cnt[i] : 0;
    sh[threadIdx.x] = v;
    __syncthreads();
    for (int off = 1; off < 256; off <<= 1) {
        int t = (threadIdx.x >= off) ? sh[threadIdx.x - off] : 0;
        __syncthreads();
        sh[threadIdx.x] += t;
        __syncthreads();
    }
    if (i < n) rowptr[i + 1] = sh[threadIdx.x];
    if (threadIdx.x == 255) bsum[blockIdx.x] = sh[255];
}

__global__ __launch_bounds__(512) void scan_partials(int* __restrict__ bsum, int nb) {
    __shared__ int sh[512];
    int tid = threadIdx.x;
    int v = (tid < nb) ? bsum[tid] : 0;
    sh[tid] = v;
    __syncthreads();
    for (int off = 1; off < 512; off <<= 1) {
        int t = (tid >= off) ? sh[tid - off] : 0;
        __syncthreads();
        sh[tid] += t;
        __syncthreads();
    }
    if (tid < nb) bsum[tid] = sh[tid] - v;  // exclusive
}

__global__ __launch_bounds__(256) void scan_add(int* __restrict__ rowptr,
                                                const int* __restrict__ bsum,
                                                const int* __restrict__ cnt,
                                                int* __restrict__ nxt, int n) {
    int i = blockIdx.x * 256 + threadIdx.x;
    if (i < n) {
        int r = rowptr[i + 1] + bsum[blockIdx.x];
        rowptr[i + 1] = r;
        nxt[i] = r - cnt[i];
        if (i == 0) rowptr[0] = 0;
    }
}

__global__ __launch_bounds__(256) void fill_csr(const int* __restrict__ src,
                                                const int* __restrict__ dst,
                                                int* __restrict__ nxt,
                                                int* __restrict__ colx, int E) {
    int e = blockIdx.x * 256 + threadIdx.x;
    if (e < E) {
        int d = dst[e];
        int pos = atomicAdd(&nxt[d], 1);
        colx[pos] = src[e];
    }
}

// ---------------- GEMM + attention logits ----------------
// ft[n, :] = h[n, :] @ W  (W: [K, FOUT] row-major)
// el[n, h] = sum_d ft[n, h*D+d] * al[h*D+d]   (al flat == col index)
// Lane owns cols (2*lane, 2*lane+1) for FOUT=128 (head = lane>>4),
// or col lane for FOUT=64 (H=1). 2 nodes per wave for W-read reuse.

template <int K, int FOUT, int H>
__global__ __launch_bounds__(256) void gemm_ft(const float* __restrict__ hin,
                                               const float* __restrict__ W,
                                               const float* __restrict__ al,
                                               const float* __restrict__ ar,
                                               float* __restrict__ ft,
                                               float* __restrict__ el,
                                               float* __restrict__ er, int nnodes) {
    __shared__ float Ws[K * FOUT];
    __shared__ float als[FOUT], ars[FOUT];
    const int tid = threadIdx.x;
    for (int i = tid; i < K * FOUT / 4; i += 256)
        ((float4*)Ws)[i] = ((const float4*)W)[i];
    if (tid < FOUT) { als[tid] = al[tid]; ars[tid] = ar[tid]; }
    __syncthreads();

    const int warp = tid >> 6, lane = tid & 63;
    const int wid = blockIdx.x * 4 + warp;
    const int n0 = wid * 2, n1 = n0 + 1;
    if (n0 >= nnodes) return;
    const bool has1 = (n1 < nnodes);

    float a0[K / 64], a1[K / 64];
#pragma unroll
    for (int q = 0; q < K / 64; ++q) {
        a0[q] = hin[(size_t)n0 * K + q * 64 + lane];
        a1[q] = has1 ? hin[(size_t)n1 * K + q * 64 + lane] : 0.f;
    }

    if constexpr (FOUT == 128) {
        float acc00 = 0, acc01 = 0, acc10 = 0, acc11 = 0;
#pragma unroll
        for (int k = 0; k < K; ++k) {
            float x0 = __shfl(a0[k >> 6], k & 63);
            float x1 = __shfl(a1[k >> 6], k & 63);
            float2 w = *(const float2*)&Ws[k * FOUT + 2 * lane];
            acc00 = fmaf(x0, w.x, acc00);
            acc01 = fmaf(x0, w.y, acc01);
            acc10 = fmaf(x1, w.x, acc10);
            acc11 = fmaf(x1, w.y, acc11);
        }
        *(float2*)&ft[(size_t)n0 * FOUT + 2 * lane] = make_float2(acc00, acc01);
        if (has1) *(float2*)&ft[(size_t)n1 * FOUT + 2 * lane] = make_float2(acc10, acc11);

        float2 alv = *(const float2*)&als[2 * lane];
        float2 arv = *(const float2*)&ars[2 * lane];
        float pl0 = acc00 * alv.x + acc01 * alv.y;
        float pr0 = acc00 * arv.x + acc01 * arv.y;
        float pl1 = acc10 * alv.x + acc11 * alv.y;
        float pr1 = acc10 * arv.x + acc11 * arv.y;
#pragma unroll
        for (int msk = 1; msk < 16; msk <<= 1) {
            pl0 += __shfl_xor(pl0, msk);
            pr0 += __shfl_xor(pr0, msk);
            pl1 += __shfl_xor(pl1, msk);
            pr1 += __shfl_xor(pr1, msk);
        }
        if ((lane & 15) == 0) {
            int h = lane >> 4;
            el[n0 * H + h] = pl0;
            er[n0 * H + h] = pr0;
            if (has1) { el[n1 * H + h] = pl1; er[n1 * H + h] = pr1; }
        }
    } else {  // FOUT == 64, H == 1
        float acc0 = 0, acc1 = 0;
#pragma unroll
        for (int k = 0; k < K; ++k) {
            float x0 = __shfl(a0[k >> 6], k & 63);
            float x1 = __shfl(a1[k >> 6], k & 63);
            float w = Ws[k * FOUT + lane];
            acc0 = fmaf(x0, w, acc0);
            acc1 = fmaf(x1, w, acc1);
        }
        ft[(size_t)n0 * FOUT + lane] = acc0;
        if (has1) ft[(size_t)n1 * FOUT + lane] = acc1;

        float pl0 = acc0 * als[lane], pr0 = acc0 * ars[lane];
        float pl1 = acc1 * als[lane], pr1 = acc1 * ars[lane];
#pragma unroll
        for (int msk = 1; msk < 64; msk <<= 1) {
            pl0 += __shfl_xor(pl0, msk);
            pr0 += __shfl_xor(pr0, msk);
            pl1 += __shfl_xor(pl1, msk);
            pr1 += __shfl_xor(pr1, msk);
        }
        if (lane == 0) {
            el[n0] = pl0; er[n0] = pr0;
            if (has1) { el[n1] = pl1; er[n1] = pr1; }
        }
    }
}

// ---------------- Edge-softmax aggregation ----------------
// One wave per dst node. Online softmax (running max m, sum s) per lane
// (lane's cols share one head). Gathers ft[src] rows (contiguous 512B/256B).

template <int F, int H, bool RELU>
__global__ __launch_bounds__(256) void gat_aggregate(
    const int* __restrict__ rowptr, const int* __restrict__ colx,
    const float* __restrict__ ft, const float* __restrict__ el,
    const float* __restrict__ er, const float* __restrict__ bias,
    float* __restrict__ out, int nnodes) {
    const int tid = threadIdx.x, warp = tid >> 6, lane = tid & 63;
    const int n = blockIdx.x * 4 + warp;
    if (n >= nnodes) return;
    const int start = rowptr[n], end = rowptr[n + 1];

    float er_s;
    int head = 0;
    if constexpr (H == 4) {
        head = lane >> 4;
        float4 e4 = *(const float4*)&er[(size_t)n * 4];
        float t0 = (head & 1) ? e4.y : e4.x;
        float t1 = (head & 1) ? e4.w : e4.z;
        er_s = (head & 2) ? t1 : t0;
    } else {
        er_s = er[n];
    }

    float m = -INFINITY, s = 0.f, acc0 = 0.f, acc1 = 0.f;

    for (int base = start; base < end; base += WAVE) {
        int cnt = min(WAVE, end - base);
        int my = (lane < cnt) ? colx[base + lane] : 0;
        for (int i = 0; i < cnt; ++i) {
            int srcn = __shfl(my, i);
            float elv;
            if constexpr (H == 4) {
                float4 e4 = *(const float4*)&el[(size_t)srcn * 4];
                float t0 = (head & 1) ? e4.y : e4.x;
                float t1 = (head & 1) ? e4.w : e4.z;
                elv = (head & 2) ? t1 : t0;
            } else {
                elv = el[srcn];
            }
            float e = elv + er_s;
            e = (e > 0.f) ? e : 0.2f * e;  // leaky_relu 0.2

            float f0, f1;
            if constexpr (F == 128) {
                float2 f = *(const float2*)&ft[(size_t)srcn * 128 + 2 * lane];
                f0 = f.x; f1 = f.y;
            } else {
                f0 = ft[(size_t)srcn * 64 + lane];
                f1 = 0.f;
            }
            float nm = fmaxf(m, e);
            float sc = __expf(m - nm);  // exp(-inf)=0 handles first edge
            float p = __expf(e - nm);
            s = s * sc + p;
            acc0 = acc0 * sc + p * f0;
            acc1 = acc1 * sc + p * f1;
            m = nm;
        }
    }

    float inv = 1.0f / s;  // deg >= 1 guaranteed
    float o0 = acc0 * inv, o1 = acc1 * inv;
    if constexpr (F == 128) {
        float2 b2 = *(const float2*)&bias[2 * lane];
        o0 += b2.x; o1 += b2.y;
        if (RELU) { o0 = fmaxf(o0, 0.f); o1 = fmaxf(o1, 0.f); }
        *(float2*)&out[(size_t)n * 128 + 2 * lane] = make_float2(o0, o1);
    } else {
        o0 += bias[lane];
        if (RELU) o0 = fmaxf(o0, 0.f);
        out[(size_t)n * 64 + lane] = o0;
    }
}

// ---------------- host launch ----------------

static inline size_t alignup(size_t x) { return (x + 255) & ~(size_t)255; }

extern "C" void kernel_launch(void* const* d_in, const int* in_sizes, int n_in,
                              void* d_out, int out_size, void* d_ws, size_t ws_size,
                              hipStream_t stream) {
    const float* features = (const float*)d_in[0];
    const int* src = (const int*)d_in[1];
    const int* dst = (const int*)d_in[2];
    const float* W0 = (const float*)d_in[3];
    const float* al0 = (const float*)d_in[4];
    const float* ar0 = (const float*)d_in[5];
    const float* b0 = (const float*)d_in[6];
    const float* W1 = (const float*)d_in[7];
    const float* al1 = (const float*)d_in[8];
    const float* ar1 = (const float*)d_in[9];
    const float* b1 = (const float*)d_in[10];
    const float* W2 = (const float*)d_in[11];
    const float* al2 = (const float*)d_in[12];
    const float* ar2 = (const float*)d_in[13];
    const float* b2 = (const float*)d_in[14];
    float* out = (float*)d_out;

    const int N = in_sizes[0] / 128;  // 100000
    const int E = in_sizes[1];        // 1600000

    char* w = (char*)d_ws;
    int* cnt = (int*)w;        w += alignup((size_t)N * 4);
    int* rowptr = (int*)w;     w += alignup((size_t)(N + 1) * 4);
    int* nxt = (int*)w;        w += alignup((size_t)N * 4);
    int* bsum = (int*)w;       w += alignup(512 * 4);
    int* colx = (int*)w;       w += alignup((size_t)E * 4);
    float* ft = (float*)w;     w += alignup((size_t)N * 128 * 4);
    float* hbuf = (float*)w;   w += alignup((size_t)N * 128 * 4);
    float* el = (float*)w;     w += alignup((size_t)N * 4 * 4);
    float* er = (float*)w;     w += alignup((size_t)N * 4 * 4);

    const int nbE = (E + 255) / 256;
    const int nbN = (N + 255) / 256;

    // CSR build
    hipMemsetAsync(cnt, 0, (size_t)N * 4, stream);
    count_deg<<<nbE, 256, 0, stream>>>(dst, cnt, E);
    scan_block<<<nbN, 256, 0, stream>>>(cnt, rowptr, bsum, N);
    scan_partials<<<1, 512, 0, stream>>>(bsum, nbN);
    scan_add<<<nbN, 256, 0, stream>>>(rowptr, bsum, cnt, nxt, N);
    fill_csr<<<nbE, 256, 0, stream>>>(src, dst, nxt, colx, E);

    const int gGemm = (N / 2 + 1 + 3) / 4;  // 2 nodes/wave, 4 waves/block
    const int gAgg = (N + 3) / 4;           // 1 node/wave

    // Layer 0: features -> ft -> hbuf (relu)
    gemm_ft<128, 128, 4><<<gGemm, 256, 0, stream>>>(features, W0, al0, ar0, ft, el, er, N);
    gat_aggregate<128, 4, true><<<gAgg, 256, 0, stream>>>(rowptr, colx, ft, el, er, b0, hbuf, N);

    // Layer 1: hbuf -> ft -> hbuf (relu)
    gemm_ft<128, 128, 4><<<gGemm, 256, 0, stream>>>(hbuf, W1, al1, ar1, ft, el, er, N);
    gat_aggregate<128, 4, true><<<gAgg, 256, 0, stream>>>(rowptr, colx, ft, el, er, b1, hbuf, N);

    // Layer 2: hbuf -> ft(64) -> out (no relu, 1 head)
    gemm_ft<128, 64, 1><<<gGemm, 256, 0, stream>>>(hbuf, W2, al2, ar2, ft, el, er, N);
    gat_aggregate<64, 1, false><<<gAgg, 256, 0, stream>>>(rowptr, colx, ft, el, er, b2, out, N);
}

// Round 2
// 847.112 us; speedup vs baseline: 1.3646x; 1.3646x over previous
//
#include <hip/hip_runtime.h>
#include <hip/hip_bf16.h>
#include <math.h>

// ---------------------------------------------------------------------------
// GAT (3-layer, DGL-style) on MI355X.
// CSR build (dst-sorted) -> per layer: register-tiled fp32 GEMM with fused
// el/er epilogue, then online-softmax aggregation with 4-way ILP.
// ---------------------------------------------------------------------------

#define WAVE 64
constexpr int KDIM = 128;

// ---------------- CSR build ----------------

__global__ __launch_bounds__(256) void count_deg(const int* __restrict__ dst,
                                                 int* __restrict__ cnt, int E) {
    int e = blockIdx.x * 256 + threadIdx.x;
    if (e < E) atomicAdd(&cnt[dst[e]], 1);
}

__global__ __launch_bounds__(256) void scan_block(const int* __restrict__ cnt,
                                                  int* __restrict__ rowptr,
                                                  int* __restrict__ bsum, int n) {
    __shared__ int sh[256];
    int i = blockIdx.x * 256 + threadIdx.x;
    int v = (i < n) ? cnt[i] : 0;
    sh[threadIdx.x] = v;
    __syncthreads();
    for (int off = 1; off < 256; off <<= 1) {
        int t = (threadIdx.x >= off) ? sh[threadIdx.x - off] : 0;
        __syncthreads();
        sh[threadIdx.x] += t;
        __syncthreads();
    }
    if (i < n) rowptr[i + 1] = sh[threadIdx.x];
    if (threadIdx.x == 255) bsum[blockIdx.x] = sh[255];
}

__global__ __launch_bounds__(512) void scan_partials(int* __restrict__ bsum, int nb) {
    __shared__ int sh[512];
    int tid = threadIdx.x;
    int v = (tid < nb) ? bsum[tid] : 0;
    sh[tid] = v;
    __syncthreads();
    for (int off = 1; off < 512; off <<= 1) {
        int t = (tid >= off) ? sh[tid - off] : 0;
        __syncthreads();
        sh[tid] += t;
        __syncthreads();
    }
    if (tid < nb) bsum[tid] = sh[tid] - v;  // exclusive
}

__global__ __launch_bounds__(256) void scan_add(int* __restrict__ rowptr,
                                                const int* __restrict__ bsum,
                                                const int* __restrict__ cnt,
                                                int* __restrict__ nxt, int n) {
    int i = blockIdx.x * 256 + threadIdx.x;
    if (i < n) {
        int r = rowptr[i + 1] + bsum[blockIdx.x];
        rowptr[i + 1] = r;
        nxt[i] = r - cnt[i];
        if (i == 0) rowptr[0] = 0;
    }
}

__global__ __launch_bounds__(256) void fill_csr(const int* __restrict__ src,
                                                const int* __restrict__ dst,
                                                int* __restrict__ nxt,
                                                int* __restrict__ colx, int E) {
    int e = blockIdx.x * 256 + threadIdx.x;
    if (e < E) {
        int d = dst[e];
        int pos = atomicAdd(&nxt[d], 1);
        colx[pos] = src[e];
    }
}

// ---------------- GEMM + attention logits ----------------
// Block: 128 nodes x FOUT cols. ht[k][node] transposed in LDS, W in LDS.
// Thread tile: TM nodes x 8 cols. Fused el/er epilogue.

template <int FOUT, int H>
__global__ __launch_bounds__(256) void gemm_ft(const float* __restrict__ hin,
                                               const float* __restrict__ W,
                                               const float* __restrict__ al,
                                               const float* __restrict__ ar,
                                               float* __restrict__ ft,
                                               float* __restrict__ el,
                                               float* __restrict__ er, int nnodes) {
    constexpr int NODES = 128;
    constexpr int TN = 8;
    constexpr int TCS = FOUT / TN;   // 16 (FOUT=128) or 8 (FOUT=64)
    constexpr int ROWS = 256 / TCS;  // 16 or 32
    constexpr int TM = NODES / ROWS; // 8 or 4

    __shared__ float ht[KDIM][NODES];   // 64 KB
    __shared__ float Ws[KDIM * FOUT];   // 64 or 32 KB

    const int tid = threadIdx.x;
    const int nb = blockIdx.x * NODES;

    // stage W (linear, coalesced)
    for (int i = tid; i < KDIM * FOUT / 4; i += 256)
        ((float4*)Ws)[i] = ((const float4*)W)[i];

    // stage h-tile transposed; zero-fill tail nodes
    {
        const int n = tid & (NODES - 1);
        const int k0base = (tid >> 7) * 4;  // 0 or 4
        const bool valid = (nb + n) < nnodes;
        for (int k0 = k0base; k0 < KDIM; k0 += 8) {
            float4 v = valid ? *(const float4*)&hin[(size_t)(nb + n) * KDIM + k0]
                             : make_float4(0.f, 0.f, 0.f, 0.f);
            ht[k0][n] = v.x; ht[k0 + 1][n] = v.y;
            ht[k0 + 2][n] = v.z; ht[k0 + 3][n] = v.w;
        }
    }
    __syncthreads();

    const int row = tid / TCS, tc = tid % TCS;
    const int nloc = row * TM;

    float acc[TM][TN];
#pragma unroll
    for (int m = 0; m < TM; ++m)
#pragma unroll
        for (int j = 0; j < TN; ++j) acc[m][j] = 0.f;

#pragma unroll 2
    for (int k = 0; k < KDIM; ++k) {
        float4 w0 = *(const float4*)&Ws[k * FOUT + tc * TN];
        float4 w1 = *(const float4*)&Ws[k * FOUT + tc * TN + 4];
        float wv[TN] = {w0.x, w0.y, w0.z, w0.w, w1.x, w1.y, w1.z, w1.w};
        float hv[TM];
        {
            float4 h0 = *(const float4*)&ht[k][nloc];
            hv[0] = h0.x; hv[1] = h0.y; hv[2] = h0.z; hv[3] = h0.w;
            if constexpr (TM == 8) {
                float4 h1 = *(const float4*)&ht[k][nloc + 4];
                hv[4] = h1.x; hv[5] = h1.y; hv[6] = h1.z; hv[7] = h1.w;
            }
        }
#pragma unroll
        for (int m = 0; m < TM; ++m)
#pragma unroll
            for (int j = 0; j < TN; ++j)
                acc[m][j] = fmaf(hv[m], wv[j], acc[m][j]);
    }

    // epilogue: store ft, fused el/er
    float alv[TN], arv[TN];
#pragma unroll
    for (int j = 0; j < TN; ++j) {
        alv[j] = al[tc * TN + j];
        arv[j] = ar[tc * TN + j];
    }
    constexpr int GROUP = (H == 4) ? 4 : TCS;  // lanes per head (tc units)

#pragma unroll
    for (int m = 0; m < TM; ++m) {
        const int n = nb + nloc + m;
        const bool valid = n < nnodes;
        float pl = 0.f, pr = 0.f;
#pragma unroll
        for (int j = 0; j < TN; ++j) {
            pl = fmaf(acc[m][j], alv[j], pl);
            pr = fmaf(acc[m][j], arv[j], pr);
        }
#pragma unroll
        for (int msk = 1; msk < GROUP; msk <<= 1) {
            pl += __shfl_xor(pl, msk);
            pr += __shfl_xor(pr, msk);
        }
        if (valid) {
            *(float4*)&ft[(size_t)n * FOUT + tc * TN] =
                make_float4(acc[m][0], acc[m][1], acc[m][2], acc[m][3]);
            *(float4*)&ft[(size_t)n * FOUT + tc * TN + 4] =
                make_float4(acc[m][4], acc[m][5], acc[m][6], acc[m][7]);
            if ((tc & (GROUP - 1)) == 0) {
                const int h = tc / GROUP;
                el[(size_t)n * H + h] = pl;
                er[(size_t)n * H + h] = pr;
            }
        }
    }
}

// ---------------- Edge-softmax aggregation ----------------
// One wave per dst node; lane owns cols (2*lane, 2*lane+1) [F=128] or col
// lane [F=64]. 4 independent online-softmax states (edges e..e+3), merged
// flash-style at the end. colx/el loads are wave-uniform broadcasts.

template <int F, int H, bool RELU>
__global__ __launch_bounds__(256) void gat_aggregate(
    const int* __restrict__ rowptr, const int* __restrict__ colx,
    const float* __restrict__ ft, const float* __restrict__ el,
    const float* __restrict__ er, const float* __restrict__ bias,
    float* __restrict__ out, int nnodes) {
    const int tid = threadIdx.x, warp = tid >> 6, lane = tid & 63;
    const int n = blockIdx.x * 4 + warp;
    if (n >= nnodes) return;
    const int start = rowptr[n], end = rowptr[n + 1];
    const int head = (H == 4) ? (lane >> 4) : 0;

    float er_s;
    if constexpr (H == 4) {
        float4 e4 = *(const float4*)&er[(size_t)n * 4];
        er_s = head == 0 ? e4.x : head == 1 ? e4.y : head == 2 ? e4.z : e4.w;
    } else {
        er_s = er[n];
    }

    float m0 = -INFINITY, m1 = -INFINITY, m2 = -INFINITY, m3 = -INFINITY;
    float s0 = 0.f, s1 = 0.f, s2 = 0.f, s3 = 0.f;
    float a0x = 0.f, a0y = 0.f, a1x = 0.f, a1y = 0.f;
    float a2x = 0.f, a2y = 0.f, a3x = 0.f, a3y = 0.f;

#define SEL_EL(srcn, dst_)                                                 \
    {                                                                      \
        if constexpr (H == 4) {                                            \
            float4 e4 = *(const float4*)&el[(size_t)(srcn)*4];             \
            dst_ = head == 0 ? e4.x : head == 1 ? e4.y                     \
                             : head == 2 ? e4.z : e4.w;                    \
        } else {                                                           \
            dst_ = el[srcn];                                               \
        }                                                                  \
    }

#define LOAD_F(srcn, fx, fy)                                               \
    {                                                                      \
        if constexpr (F == 128) {                                          \
            float2 f_ = *(const float2*)&ft[(size_t)(srcn)*128 + 2*lane];  \
            fx = f_.x; fy = f_.y;                                          \
        } else {                                                           \
            fx = ft[(size_t)(srcn)*64 + lane]; fy = 0.f;                   \
        }                                                                  \
    }

#define UPD(mj, sj, ax, ay, xv, fx, fy)                                    \
    {                                                                      \
        float nm = fmaxf(mj, xv);                                          \
        float sc = __expf(mj - nm);                                        \
        float p = __expf(xv - nm);                                         \
        sj = sj * sc + p;                                                  \
        ax = ax * sc + p * (fx);                                           \
        ay = ay * sc + p * (fy);                                           \
        mj = nm;                                                           \
    }

    int e = start;
    for (; e + 4 <= end; e += 4) {
        int i0 = colx[e], i1 = colx[e + 1], i2 = colx[e + 2], i3 = colx[e + 3];
        float x0, x1, x2, x3;
        SEL_EL(i0, x0); SEL_EL(i1, x1); SEL_EL(i2, x2); SEL_EL(i3, x3);
        x0 += er_s; x0 = (x0 > 0.f) ? x0 : 0.2f * x0;
        x1 += er_s; x1 = (x1 > 0.f) ? x1 : 0.2f * x1;
        x2 += er_s; x2 = (x2 > 0.f) ? x2 : 0.2f * x2;
        x3 += er_s; x3 = (x3 > 0.f) ? x3 : 0.2f * x3;
        float f0x, f0y, f1x, f1y, f2x, f2y, f3x, f3y;
        LOAD_F(i0, f0x, f0y); LOAD_F(i1, f1x, f1y);
        LOAD_F(i2, f2x, f2y); LOAD_F(i3, f3x, f3y);
        UPD(m0, s0, a0x, a0y, x0, f0x, f0y);
        UPD(m1, s1, a1x, a1y, x1, f1x, f1y);
        UPD(m2, s2, a2x, a2y, x2, f2x, f2y);
        UPD(m3, s3, a3x, a3y, x3, f3x, f3y);
    }
    for (; e < end; ++e) {
        int i0 = colx[e];
        float x0;
        SEL_EL(i0, x0);
        x0 += er_s; x0 = (x0 > 0.f) ? x0 : 0.2f * x0;
        float f0x, f0y;
        LOAD_F(i0, f0x, f0y);
        UPD(m0, s0, a0x, a0y, x0, f0x, f0y);
    }

    // flash-merge the 4 states (unused states have m=-inf -> weight 0)
    float M = fmaxf(fmaxf(m0, m1), fmaxf(m2, m3));
    float c0 = __expf(m0 - M), c1 = __expf(m1 - M);
    float c2 = __expf(m2 - M), c3 = __expf(m3 - M);
    float s = s0 * c0 + s1 * c1 + s2 * c2 + s3 * c3;
    float ox = a0x * c0 + a1x * c1 + a2x * c2 + a3x * c3;
    float oy = a0y * c0 + a1y * c1 + a2y * c2 + a3y * c3;

    float inv = 1.0f / s;
    ox *= inv; oy *= inv;
    if constexpr (F == 128) {
        float2 b2 = *(const float2*)&bias[2 * lane];
        ox += b2.x; oy += b2.y;
        if (RELU) { ox = fmaxf(ox, 0.f); oy = fmaxf(oy, 0.f); }
        *(float2*)&out[(size_t)n * 128 + 2 * lane] = make_float2(ox, oy);
    } else {
        ox += bias[lane];
        if (RELU) ox = fmaxf(ox, 0.f);
        out[(size_t)n * 64 + lane] = ox;
    }
#undef SEL_EL
#undef LOAD_F
#undef UPD
}

// ---------------- host launch ----------------

static inline size_t alignup(size_t x) { return (x + 255) & ~(size_t)255; }

extern "C" void kernel_launch(void* const* d_in, const int* in_sizes, int n_in,
                              void* d_out, int out_size, void* d_ws, size_t ws_size,
                              hipStream_t stream) {
    const float* features = (const float*)d_in[0];
    const int* src = (const int*)d_in[1];
    const int* dst = (const int*)d_in[2];
    const float* W0 = (const float*)d_in[3];
    const float* al0 = (const float*)d_in[4];
    const float* ar0 = (const float*)d_in[5];
    const float* b0 = (const float*)d_in[6];
    const float* W1 = (const float*)d_in[7];
    const float* al1 = (const float*)d_in[8];
    const float* ar1 = (const float*)d_in[9];
    const float* b1 = (const float*)d_in[10];
    const float* W2 = (const float*)d_in[11];
    const float* al2 = (const float*)d_in[12];
    const float* ar2 = (const float*)d_in[13];
    const float* b2 = (const float*)d_in[14];
    float* out = (float*)d_out;

    const int N = in_sizes[0] / 128;  // 100000
    const int E = in_sizes[1];        // 1600000

    char* w = (char*)d_ws;
    int* cnt = (int*)w;        w += alignup((size_t)N * 4);
    int* rowptr = (int*)w;     w += alignup((size_t)(N + 1) * 4);
    int* nxt = (int*)w;        w += alignup((size_t)N * 4);
    int* bsum = (int*)w;       w += alignup(512 * 4);
    int* colx = (int*)w;       w += alignup((size_t)E * 4);
    float* ft = (float*)w;     w += alignup((size_t)N * 128 * 4);
    float* hbuf = (float*)w;   w += alignup((size_t)N * 128 * 4);
    float* el = (float*)w;     w += alignup((size_t)N * 4 * 4);
    float* er = (float*)w;     w += alignup((size_t)N * 4 * 4);

    const int nbE = (E + 255) / 256;
    const int nbN = (N + 255) / 256;

    // CSR build
    hipMemsetAsync(cnt, 0, (size_t)N * 4, stream);
    count_deg<<<nbE, 256, 0, stream>>>(dst, cnt, E);
    scan_block<<<nbN, 256, 0, stream>>>(cnt, rowptr, bsum, N);
    scan_partials<<<1, 512, 0, stream>>>(bsum, nbN);
    scan_add<<<nbN, 256, 0, stream>>>(rowptr, bsum, cnt, nxt, N);
    fill_csr<<<nbE, 256, 0, stream>>>(src, dst, nxt, colx, E);

    const int gGemm = (N + 127) / 128;
    const int gAgg = (N + 3) / 4;

    // Layer 0
    gemm_ft<128, 4><<<gGemm, 256, 0, stream>>>(features, W0, al0, ar0, ft, el, er, N);
    gat_aggregate<128, 4, true><<<gAgg, 256, 0, stream>>>(rowptr, colx, ft, el, er, b0, hbuf, N);

    // Layer 1
    gemm_ft<128, 4><<<gGemm, 256, 0, stream>>>(hbuf, W1, al1, ar1, ft, el, er, N);
    gat_aggregate<128, 4, true><<<gAgg, 256, 0, stream>>>(rowptr, colx, ft, el, er, b1, hbuf, N);

    // Layer 2
    gemm_ft<64, 1><<<gGemm, 256, 0, stream>>>(hbuf, W2, al2, ar2, ft, el, er, N);
    gat_aggregate<64, 1, false><<<gAgg, 256, 0, stream>>>(rowptr, colx, ft, el, er, b2, out, N);
}

// Round 3
// 809.725 us; speedup vs baseline: 1.4276x; 1.0462x over previous
//
#include <hip/hip_runtime.h>
#include <hip/hip_bf16.h>
#include <math.h>

// ---------------------------------------------------------------------------
// GAT (3-layer, DGL-style) on MI355X.
// CSR build (dst-sorted) -> per layer:
//   gemm_ft: K-tiled (BK=32) fp32 register GEMM, 128x FOUT block tile,
//            33KB LDS -> 4 blocks/CU, fused el/er epilogue.
//   gat_aggregate: single-pass exp-weighted aggregation (no max-subtraction:
//            logits provably |e| < ~5, exp is safe in fp32; normalization at
//            the end makes it mathematically identical to softmax), 8-wide
//            unrolled gather for MLP.
// ---------------------------------------------------------------------------

#define WAVE 64
constexpr int KDIM = 128;

// ---------------- CSR build ----------------

__global__ __launch_bounds__(256) void count_deg(const int* __restrict__ dst,
                                                 int* __restrict__ cnt, int E) {
    int e = blockIdx.x * 256 + threadIdx.x;
    if (e < E) atomicAdd(&cnt[dst[e]], 1);
}

__global__ __launch_bounds__(256) void scan_block(const int* __restrict__ cnt,
                                                  int* __restrict__ rowptr,
                                                  int* __restrict__ bsum, int n) {
    __shared__ int sh[256];
    int i = blockIdx.x * 256 + threadIdx.x;
    int v = (i < n) ? cnt[i] : 0;
    sh[threadIdx.x] = v;
    __syncthreads();
    for (int off = 1; off < 256; off <<= 1) {
        int t = (threadIdx.x >= off) ? sh[threadIdx.x - off] : 0;
        __syncthreads();
        sh[threadIdx.x] += t;
        __syncthreads();
    }
    if (i < n) rowptr[i + 1] = sh[threadIdx.x];
    if (threadIdx.x == 255) bsum[blockIdx.x] = sh[255];
}

__global__ __launch_bounds__(512) void scan_partials(int* __restrict__ bsum, int nb) {
    __shared__ int sh[512];
    int tid = threadIdx.x;
    int v = (tid < nb) ? bsum[tid] : 0;
    sh[tid] = v;
    __syncthreads();
    for (int off = 1; off < 512; off <<= 1) {
        int t = (tid >= off) ? sh[tid - off] : 0;
        __syncthreads();
        sh[tid] += t;
        __syncthreads();
    }
    if (tid < nb) bsum[tid] = sh[tid] - v;  // exclusive
}

__global__ __launch_bounds__(256) void scan_add(int* __restrict__ rowptr,
                                                const int* __restrict__ bsum,
                                                const int* __restrict__ cnt,
                                                int* __restrict__ nxt, int n) {
    int i = blockIdx.x * 256 + threadIdx.x;
    if (i < n) {
        int r = rowptr[i + 1] + bsum[blockIdx.x];
        rowptr[i + 1] = r;
        nxt[i] = r - cnt[i];
        if (i == 0) rowptr[0] = 0;
    }
}

__global__ __launch_bounds__(256) void fill_csr(const int* __restrict__ src,
                                                const int* __restrict__ dst,
                                                int* __restrict__ nxt,
                                                int* __restrict__ colx, int E) {
    int e = blockIdx.x * 256 + threadIdx.x;
    if (e < E) {
        int d = dst[e];
        int pos = atomicAdd(&nxt[d], 1);
        colx[pos] = src[e];
    }
}

// ---------------- GEMM + attention logits ----------------
// Block tile: 128 nodes x FOUT. BK=32 K-chunks. Thread (tc=tid&15,row=tid>>4)
// owns rows {row*4+m, 64+row*4+m} x cols {tc*4+j (, 64+tc*4+j)}.
// ht stored transposed+padded (LDH=132): conflict-free broadcast reads.

template <int FOUT, int H>
__global__ __launch_bounds__(256, 4) void gemm_ft(
    const float* __restrict__ hin, const float* __restrict__ W,
    const float* __restrict__ al, const float* __restrict__ ar,
    float* __restrict__ ft, float* __restrict__ el, float* __restrict__ er,
    int nnodes) {
    constexpr int NODES = 128;
    constexpr int BK = 32;
    constexpr int LDH = 132;                  // padded (floats), 16B-aligned rows
    constexpr int TN = (FOUT == 128) ? 8 : 4; // cols per thread

    __shared__ float ht[BK * LDH];   // 16.5 KB
    __shared__ float Ws[BK * FOUT];  // 16 KB (128) / 8 KB (64)

    const int tid = threadIdx.x;
    const int nb = blockIdx.x * NODES;
    const int tc = tid & 15, row = tid >> 4;

    float acc[8][TN];
#pragma unroll
    for (int m = 0; m < 8; ++m)
#pragma unroll
        for (int j = 0; j < TN; ++j) acc[m][j] = 0.f;

    const int nl = tid >> 3;          // 0..31
    const int kq = (tid & 7) * 4;     // 0,4,..,28

    for (int k0 = 0; k0 < KDIM; k0 += BK) {
        // stage h-tile transposed
#pragma unroll
        for (int it = 0; it < 4; ++it) {
            int nn = nl + it * 32;
            int n = nb + nn;
            float4 v = (n < nnodes)
                           ? *(const float4*)&hin[(size_t)n * KDIM + k0 + kq]
                           : make_float4(0.f, 0.f, 0.f, 0.f);
            ht[(kq + 0) * LDH + nn] = v.x;
            ht[(kq + 1) * LDH + nn] = v.y;
            ht[(kq + 2) * LDH + nn] = v.z;
            ht[(kq + 3) * LDH + nn] = v.w;
        }
        // stage W chunk (rows k0..k0+31 contiguous)
        {
            const float4* Wg = (const float4*)&W[(size_t)k0 * FOUT];
#pragma unroll
            for (int it = 0; it < BK * FOUT / 1024; ++it)
                ((float4*)Ws)[tid + it * 256] = Wg[tid + it * 256];
        }
        __syncthreads();

#pragma unroll 4
        for (int kk = 0; kk < BK; ++kk) {
            float4 h0 = *(const float4*)&ht[kk * LDH + row * 4];
            float4 h1 = *(const float4*)&ht[kk * LDH + 64 + row * 4];
            float hv[8] = {h0.x, h0.y, h0.z, h0.w, h1.x, h1.y, h1.z, h1.w};
            float4 w0 = *(const float4*)&Ws[kk * FOUT + tc * 4];
            float wv[TN];
            wv[0] = w0.x; wv[1] = w0.y; wv[2] = w0.z; wv[3] = w0.w;
            if constexpr (FOUT == 128) {
                float4 w1 = *(const float4*)&Ws[kk * FOUT + 64 + tc * 4];
                wv[4] = w1.x; wv[5] = w1.y; wv[6] = w1.z; wv[7] = w1.w;
            }
#pragma unroll
            for (int m = 0; m < 8; ++m)
#pragma unroll
                for (int j = 0; j < TN; ++j)
                    acc[m][j] = fmaf(hv[m], wv[j], acc[m][j]);
        }
        __syncthreads();
    }

    // epilogue: store ft + fused el/er
    float alv[TN], arv[TN];
#pragma unroll
    for (int j = 0; j < 4; ++j) {
        alv[j] = al[tc * 4 + j];
        arv[j] = ar[tc * 4 + j];
    }
    if constexpr (FOUT == 128) {
#pragma unroll
        for (int j = 0; j < 4; ++j) {
            alv[4 + j] = al[64 + tc * 4 + j];
            arv[4 + j] = ar[64 + tc * 4 + j];
        }
    }

#pragma unroll
    for (int m = 0; m < 8; ++m) {
        const int r = (m < 4) ? (row * 4 + m) : (64 + row * 4 + m - 4);
        const int n = nb + r;
        const bool valid = n < nnodes;

        float pl0 = 0.f, pr0 = 0.f, pl1 = 0.f, pr1 = 0.f;
#pragma unroll
        for (int j = 0; j < 4; ++j) {
            pl0 = fmaf(acc[m][j], alv[j], pl0);
            pr0 = fmaf(acc[m][j], arv[j], pr0);
        }
        if constexpr (FOUT == 128) {
#pragma unroll
            for (int j = 0; j < 4; ++j) {
                pl1 = fmaf(acc[m][4 + j], alv[4 + j], pl1);
                pr1 = fmaf(acc[m][4 + j], arv[4 + j], pr1);
            }
        }

        if constexpr (H == 4) {
            // heads: group0 -> tc<8 ? 0 : 1 ; group1 -> tc<8 ? 2 : 3
#pragma unroll
            for (int msk = 1; msk < 8; msk <<= 1) {
                pl0 += __shfl_xor(pl0, msk);
                pr0 += __shfl_xor(pr0, msk);
                pl1 += __shfl_xor(pl1, msk);
                pr1 += __shfl_xor(pr1, msk);
            }
            if (valid && (tc == 0 || tc == 8)) {
                int hbase = (tc == 0) ? 0 : 1;
                el[(size_t)n * 4 + hbase] = pl0;
                er[(size_t)n * 4 + hbase] = pr0;
                el[(size_t)n * 4 + hbase + 2] = pl1;
                er[(size_t)n * 4 + hbase + 2] = pr1;
            }
        } else {
#pragma unroll
            for (int msk = 1; msk < 16; msk <<= 1) {
                pl0 += __shfl_xor(pl0, msk);
                pr0 += __shfl_xor(pr0, msk);
            }
            if (valid && tc == 0) {
                el[n] = pl0;
                er[n] = pr0;
            }
        }

        if (valid) {
            *(float4*)&ft[(size_t)n * FOUT + tc * 4] =
                make_float4(acc[m][0], acc[m][1], acc[m][2], acc[m][3]);
            if constexpr (FOUT == 128)
                *(float4*)&ft[(size_t)n * FOUT + 64 + tc * 4] =
                    make_float4(acc[m][4], acc[m][5], acc[m][6], acc[m][7]);
        }
    }
}

// ---------------- Edge-softmax aggregation (single-pass, no max) ----------
// One wave per dst node. p = exp(leaky(el[src]+er[dst])); acc += p*ft[src];
// s += p; out = acc/s + b. Logits are bounded (|e| < ~5) so exp is safe.

template <int F, int H, bool RELU>
__global__ __launch_bounds__(256) void gat_aggregate(
    const int* __restrict__ rowptr, const int* __restrict__ colx,
    const float* __restrict__ ft, const float* __restrict__ el,
    const float* __restrict__ er, const float* __restrict__ bias,
    float* __restrict__ out, int nnodes) {
    const int tid = threadIdx.x, warp = tid >> 6, lane = tid & 63;
    const int n = blockIdx.x * 4 + warp;
    if (n >= nnodes) return;
    const int start = rowptr[n], end = rowptr[n + 1];
    const int head = (H == 4) ? (lane >> 4) : 0;

    float er_s;
    if constexpr (H == 4) {
        float4 e4 = *(const float4*)&er[(size_t)n * 4];
        er_s = head == 0 ? e4.x : head == 1 ? e4.y : head == 2 ? e4.z : e4.w;
    } else {
        er_s = er[n];
    }

    float sA = 0.f, sB = 0.f;
    float aAx = 0.f, aAy = 0.f, aBx = 0.f, aBy = 0.f;

#define EDGE(i_, sacc, ax, ay)                                              \
    {                                                                       \
        int sn = colx[e + (i_)];                                            \
        float x;                                                            \
        if constexpr (H == 4) {                                             \
            float4 le = *(const float4*)&el[(size_t)sn * 4];                \
            x = head == 0 ? le.x : head == 1 ? le.y : head == 2 ? le.z      \
                                                                : le.w;     \
        } else {                                                            \
            x = el[sn];                                                     \
        }                                                                   \
        x += er_s;                                                          \
        x = fmaxf(x, 0.2f * x); /* leaky_relu */                            \
        float p = __expf(x);                                                \
        sacc += p;                                                          \
        if constexpr (F == 128) {                                           \
            float2 f = *(const float2*)&ft[(size_t)sn * 128 + 2 * lane];    \
            ax = fmaf(p, f.x, ax);                                          \
            ay = fmaf(p, f.y, ay);                                          \
        } else {                                                            \
            float f = ft[(size_t)sn * 64 + lane];                           \
            ax = fmaf(p, f, ax);                                            \
        }                                                                   \
    }

    int e = start;
    for (; e + 8 <= end; e += 8) {
        EDGE(0, sA, aAx, aAy)
        EDGE(1, sB, aBx, aBy)
        EDGE(2, sA, aAx, aAy)
        EDGE(3, sB, aBx, aBy)
        EDGE(4, sA, aAx, aAy)
        EDGE(5, sB, aBx, aBy)
        EDGE(6, sA, aAx, aAy)
        EDGE(7, sB, aBx, aBy)
    }
    for (; e < end; ++e) { EDGE(0, sA, aAx, aAy) }
#undef EDGE

    float s = sA + sB;
    float inv = 1.0f / s;  // deg >= 1 guaranteed
    float ox = (aAx + aBx) * inv;
    float oy = (aAy + aBy) * inv;

    if constexpr (F == 128) {
        float2 b2 = *(const float2*)&bias[2 * lane];
        ox += b2.x; oy += b2.y;
        if (RELU) { ox = fmaxf(ox, 0.f); oy = fmaxf(oy, 0.f); }
        *(float2*)&out[(size_t)n * 128 + 2 * lane] = make_float2(ox, oy);
    } else {
        ox += bias[lane];
        if (RELU) ox = fmaxf(ox, 0.f);
        out[(size_t)n * 64 + lane] = ox;
    }
}

// ---------------- host launch ----------------

static inline size_t alignup(size_t x) { return (x + 255) & ~(size_t)255; }

extern "C" void kernel_launch(void* const* d_in, const int* in_sizes, int n_in,
                              void* d_out, int out_size, void* d_ws, size_t ws_size,
                              hipStream_t stream) {
    const float* features = (const float*)d_in[0];
    const int* src = (const int*)d_in[1];
    const int* dst = (const int*)d_in[2];
    const float* W0 = (const float*)d_in[3];
    const float* al0 = (const float*)d_in[4];
    const float* ar0 = (const float*)d_in[5];
    const float* b0 = (const float*)d_in[6];
    const float* W1 = (const float*)d_in[7];
    const float* al1 = (const float*)d_in[8];
    const float* ar1 = (const float*)d_in[9];
    const float* b1 = (const float*)d_in[10];
    const float* W2 = (const float*)d_in[11];
    const float* al2 = (const float*)d_in[12];
    const float* ar2 = (const float*)d_in[13];
    const float* b2 = (const float*)d_in[14];
    float* out = (float*)d_out;

    const int N = in_sizes[0] / 128;  // 100000
    const int E = in_sizes[1];        // 1600000

    char* w = (char*)d_ws;
    int* cnt = (int*)w;        w += alignup((size_t)N * 4);
    int* rowptr = (int*)w;     w += alignup((size_t)(N + 1) * 4);
    int* nxt = (int*)w;        w += alignup((size_t)N * 4);
    int* bsum = (int*)w;       w += alignup(512 * 4);
    int* colx = (int*)w;       w += alignup((size_t)E * 4);
    float* ft = (float*)w;     w += alignup((size_t)N * 128 * 4);
    float* hbuf = (float*)w;   w += alignup((size_t)N * 128 * 4);
    float* el = (float*)w;     w += alignup((size_t)N * 4 * 4);
    float* er = (float*)w;     w += alignup((size_t)N * 4 * 4);

    const int nbE = (E + 255) / 256;
    const int nbN = (N + 255) / 256;

    // CSR build
    hipMemsetAsync(cnt, 0, (size_t)N * 4, stream);
    count_deg<<<nbE, 256, 0, stream>>>(dst, cnt, E);
    scan_block<<<nbN, 256, 0, stream>>>(cnt, rowptr, bsum, N);
    scan_partials<<<1, 512, 0, stream>>>(bsum, nbN);
    scan_add<<<nbN, 256, 0, stream>>>(rowptr, bsum, cnt, nxt, N);
    fill_csr<<<nbE, 256, 0, stream>>>(src, dst, nxt, colx, E);

    const int gGemm = (N + 127) / 128;
    const int gAgg = (N + 3) / 4;

    // Layer 0
    gemm_ft<128, 4><<<gGemm, 256, 0, stream>>>(features, W0, al0, ar0, ft, el, er, N);
    gat_aggregate<128, 4, true><<<gAgg, 256, 0, stream>>>(rowptr, colx, ft, el, er, b0, hbuf, N);

    // Layer 1
    gemm_ft<128, 4><<<gGemm, 256, 0, stream>>>(hbuf, W1, al1, ar1, ft, el, er, N);
    gat_aggregate<128, 4, true><<<gAgg, 256, 0, stream>>>(rowptr, colx, ft, el, er, b1, hbuf, N);

    // Layer 2
    gemm_ft<64, 1><<<gGemm, 256, 0, stream>>>(hbuf, W2, al2, ar2, ft, el, er, N);
    gat_aggregate<64, 1, false><<<gAgg, 256, 0, stream>>>(rowptr, colx, ft, el, er, b2, out, N);
}

// Round 4
// 655.713 us; speedup vs baseline: 1.7629x; 1.2349x over previous
//
#include <hip/hip_runtime.h>
#include <hip/hip_bf16.h>
#include <math.h>

// ---------------------------------------------------------------------------
// GAT (3-layer, DGL-style) on MI355X.
// CSR build (dst-sorted) -> per layer:
//   gemm_ft: K-tiled (BK=32) fp32 register GEMM, 128 x FOUT block tile,
//            ~33KB LDS -> 4 blocks/CU, fused el/er epilogue.
//   gat_aggregate: single-pass exp-weighted aggregation (logits bounded,
//            no max-subtraction needed), 8-wide batched gathers with
//            index software-pipelining and masked tail for max MLP.
// ---------------------------------------------------------------------------

#define WAVE 64
constexpr int KDIM = 128;

// ---------------- CSR build ----------------

__global__ __launch_bounds__(256) void count_deg(const int* __restrict__ dst,
                                                 int* __restrict__ cnt, int E) {
    int e = blockIdx.x * 256 + threadIdx.x;
    if (e < E) atomicAdd(&cnt[dst[e]], 1);
}

__global__ __launch_bounds__(256) void scan_block(const int* __restrict__ cnt,
                                                  int* __restrict__ rowptr,
                                                  int* __restrict__ bsum, int n) {
    __shared__ int sh[256];
    int i = blockIdx.x * 256 + threadIdx.x;
    int v = (i < n) ? cnt[i] : 0;
    sh[threadIdx.x] = v;
    __syncthreads();
    for (int off = 1; off < 256; off <<= 1) {
        int t = (threadIdx.x >= off) ? sh[threadIdx.x - off] : 0;
        __syncthreads();
        sh[threadIdx.x] += t;
        __syncthreads();
    }
    if (i < n) rowptr[i + 1] = sh[threadIdx.x];
    if (threadIdx.x == 255) bsum[blockIdx.x] = sh[255];
}

__global__ __launch_bounds__(512) void scan_partials(int* __restrict__ bsum, int nb) {
    __shared__ int sh[512];
    int tid = threadIdx.x;
    int v = (tid < nb) ? bsum[tid] : 0;
    sh[tid] = v;
    __syncthreads();
    for (int off = 1; off < 512; off <<= 1) {
        int t = (tid >= off) ? sh[tid - off] : 0;
        __syncthreads();
        sh[tid] += t;
        __syncthreads();
    }
    if (tid < nb) bsum[tid] = sh[tid] - v;  // exclusive
}

__global__ __launch_bounds__(256) void scan_add(int* __restrict__ rowptr,
                                                const int* __restrict__ bsum,
                                                const int* __restrict__ cnt,
                                                int* __restrict__ nxt, int n) {
    int i = blockIdx.x * 256 + threadIdx.x;
    if (i < n) {
        int r = rowptr[i + 1] + bsum[blockIdx.x];
        rowptr[i + 1] = r;
        nxt[i] = r - cnt[i];
        if (i == 0) rowptr[0] = 0;
    }
}

__global__ __launch_bounds__(256) void fill_csr(const int* __restrict__ src,
                                                const int* __restrict__ dst,
                                                int* __restrict__ nxt,
                                                int* __restrict__ colx, int E) {
    int e = blockIdx.x * 256 + threadIdx.x;
    if (e < E) {
        int d = dst[e];
        int pos = atomicAdd(&nxt[d], 1);
        colx[pos] = src[e];
    }
}

// ---------------- GEMM + attention logits ----------------

template <int FOUT, int H>
__global__ __launch_bounds__(256, 4) void gemm_ft(
    const float* __restrict__ hin, const float* __restrict__ W,
    const float* __restrict__ al, const float* __restrict__ ar,
    float* __restrict__ ft, float* __restrict__ el, float* __restrict__ er,
    int nnodes) {
    constexpr int NODES = 128;
    constexpr int BK = 32;
    constexpr int LDH = 132;                  // padded (floats)
    constexpr int TN = (FOUT == 128) ? 8 : 4; // cols per thread

    __shared__ float ht[BK * LDH];   // 16.5 KB
    __shared__ float Ws[BK * FOUT];  // 16 KB (128) / 8 KB (64)

    const int tid = threadIdx.x;
    const int nb = blockIdx.x * NODES;
    const int tc = tid & 15, row = tid >> 4;

    float acc[8][TN];
#pragma unroll
    for (int m = 0; m < 8; ++m)
#pragma unroll
        for (int j = 0; j < TN; ++j) acc[m][j] = 0.f;

    const int nl = tid >> 3;          // 0..31
    const int kq = (tid & 7) * 4;     // 0,4,..,28

    for (int k0 = 0; k0 < KDIM; k0 += BK) {
#pragma unroll
        for (int it = 0; it < 4; ++it) {
            int nn = nl + it * 32;
            int n = nb + nn;
            float4 v = (n < nnodes)
                           ? *(const float4*)&hin[(size_t)n * KDIM + k0 + kq]
                           : make_float4(0.f, 0.f, 0.f, 0.f);
            ht[(kq + 0) * LDH + nn] = v.x;
            ht[(kq + 1) * LDH + nn] = v.y;
            ht[(kq + 2) * LDH + nn] = v.z;
            ht[(kq + 3) * LDH + nn] = v.w;
        }
        {
            const float4* Wg = (const float4*)&W[(size_t)k0 * FOUT];
#pragma unroll
            for (int it = 0; it < BK * FOUT / 1024; ++it)
                ((float4*)Ws)[tid + it * 256] = Wg[tid + it * 256];
        }
        __syncthreads();

#pragma unroll 4
        for (int kk = 0; kk < BK; ++kk) {
            float4 h0 = *(const float4*)&ht[kk * LDH + row * 4];
            float4 h1 = *(const float4*)&ht[kk * LDH + 64 + row * 4];
            float hv[8] = {h0.x, h0.y, h0.z, h0.w, h1.x, h1.y, h1.z, h1.w};
            float4 w0 = *(const float4*)&Ws[kk * FOUT + tc * 4];
            float wv[TN];
            wv[0] = w0.x; wv[1] = w0.y; wv[2] = w0.z; wv[3] = w0.w;
            if constexpr (FOUT == 128) {
                float4 w1 = *(const float4*)&Ws[kk * FOUT + 64 + tc * 4];
                wv[4] = w1.x; wv[5] = w1.y; wv[6] = w1.z; wv[7] = w1.w;
            }
#pragma unroll
            for (int m = 0; m < 8; ++m)
#pragma unroll
                for (int j = 0; j < TN; ++j)
                    acc[m][j] = fmaf(hv[m], wv[j], acc[m][j]);
        }
        __syncthreads();
    }

    float alv[TN], arv[TN];
#pragma unroll
    for (int j = 0; j < 4; ++j) {
        alv[j] = al[tc * 4 + j];
        arv[j] = ar[tc * 4 + j];
    }
    if constexpr (FOUT == 128) {
#pragma unroll
        for (int j = 0; j < 4; ++j) {
            alv[4 + j] = al[64 + tc * 4 + j];
            arv[4 + j] = ar[64 + tc * 4 + j];
        }
    }

#pragma unroll
    for (int m = 0; m < 8; ++m) {
        const int r = (m < 4) ? (row * 4 + m) : (64 + row * 4 + m - 4);
        const int n = nb + r;
        const bool valid = n < nnodes;

        float pl0 = 0.f, pr0 = 0.f, pl1 = 0.f, pr1 = 0.f;
#pragma unroll
        for (int j = 0; j < 4; ++j) {
            pl0 = fmaf(acc[m][j], alv[j], pl0);
            pr0 = fmaf(acc[m][j], arv[j], pr0);
        }
        if constexpr (FOUT == 128) {
#pragma unroll
            for (int j = 0; j < 4; ++j) {
                pl1 = fmaf(acc[m][4 + j], alv[4 + j], pl1);
                pr1 = fmaf(acc[m][4 + j], arv[4 + j], pr1);
            }
        }

        if constexpr (H == 4) {
#pragma unroll
            for (int msk = 1; msk < 8; msk <<= 1) {
                pl0 += __shfl_xor(pl0, msk);
                pr0 += __shfl_xor(pr0, msk);
                pl1 += __shfl_xor(pl1, msk);
                pr1 += __shfl_xor(pr1, msk);
            }
            if (valid && (tc == 0 || tc == 8)) {
                int hbase = (tc == 0) ? 0 : 1;
                el[(size_t)n * 4 + hbase] = pl0;
                er[(size_t)n * 4 + hbase] = pr0;
                el[(size_t)n * 4 + hbase + 2] = pl1;
                er[(size_t)n * 4 + hbase + 2] = pr1;
            }
        } else {
#pragma unroll
            for (int msk = 1; msk < 16; msk <<= 1) {
                pl0 += __shfl_xor(pl0, msk);
                pr0 += __shfl_xor(pr0, msk);
            }
            if (valid && tc == 0) {
                el[n] = pl0;
                er[n] = pr0;
            }
        }

        if (valid) {
            *(float4*)&ft[(size_t)n * FOUT + tc * 4] =
                make_float4(acc[m][0], acc[m][1], acc[m][2], acc[m][3]);
            if constexpr (FOUT == 128)
                *(float4*)&ft[(size_t)n * FOUT + 64 + tc * 4] =
                    make_float4(acc[m][4], acc[m][5], acc[m][6], acc[m][7]);
        }
    }
}

// ---------------- Edge-softmax aggregation ----------------
// One wave per dst node. 8-wide batches: issue all 8 ft gathers (long
// latency) first, then 8 el gathers, then prefetch next 8 indices, then
// compute. Tail masked via idx=-1 -> p=0 (no serial remainder loop).

template <int F, int H, bool RELU>
__global__ __launch_bounds__(256) void gat_aggregate(
    const int* __restrict__ rowptr, const int* __restrict__ colx,
    const float* __restrict__ ft, const float* __restrict__ el,
    const float* __restrict__ er, const float* __restrict__ bias,
    float* __restrict__ out, int nnodes) {
    constexpr int UN = 8;
    const int tid = threadIdx.x, warp = tid >> 6, lane = tid & 63;
    const int n = blockIdx.x * 4 + warp;
    if (n >= nnodes) return;
    const int start = rowptr[n], end = rowptr[n + 1];
    const int head = (H == 4) ? (lane >> 4) : 0;

    const float er_s = (H == 4) ? er[(size_t)n * 4 + head] : er[n];

    float sA = 0.f, sB = 0.f;
    float aAx = 0.f, aAy = 0.f, aBx = 0.f, aBy = 0.f;

    int idx[UN];
#pragma unroll
    for (int i = 0; i < UN; ++i) {
        int ee = start + i;
        idx[i] = (ee < end) ? colx[ee] : -1;
    }
    const int nit = (end - start + UN - 1) / UN;

    for (int it = 0; it < nit; ++it) {
        // 1) long-latency ft gathers first (8 independent, all in flight)
        float fx[UN], fy[UN];
#pragma unroll
        for (int i = 0; i < UN; ++i) {
            int sn = (idx[i] < 0) ? 0 : idx[i];
            if constexpr (F == 128) {
                float2 f = *(const float2*)&ft[(size_t)sn * 128 + 2 * lane];
                fx[i] = f.x; fy[i] = f.y;
            } else {
                fx[i] = ft[(size_t)sn * 64 + lane];
                fy[i] = 0.f;
            }
        }
        // 2) el gathers (L2-resident scalar)
        float xl[UN];
#pragma unroll
        for (int i = 0; i < UN; ++i) {
            int sn = (idx[i] < 0) ? 0 : idx[i];
            xl[i] = (H == 4) ? el[(size_t)sn * 4 + head] : el[sn];
        }
        // 3) software-pipeline: prefetch next batch of indices
        int nidx[UN];
        {
            int base2 = start + (it + 1) * UN;
#pragma unroll
            for (int i = 0; i < UN; ++i) {
                int ee = base2 + i;
                nidx[i] = (ee < end) ? colx[ee] : -1;
            }
        }
        // 4) compute
#pragma unroll
        for (int i = 0; i < UN; ++i) {
            float x = xl[i] + er_s;
            x = fmaxf(x, 0.2f * x);  // leaky_relu
            float p = __expf(x);
            p = (idx[i] >= 0) ? p : 0.f;
            if (i & 1) {
                sB += p;
                aBx = fmaf(p, fx[i], aBx);
                if constexpr (F == 128) aBy = fmaf(p, fy[i], aBy);
            } else {
                sA += p;
                aAx = fmaf(p, fx[i], aAx);
                if constexpr (F == 128) aAy = fmaf(p, fy[i], aAy);
            }
        }
#pragma unroll
        for (int i = 0; i < UN; ++i) idx[i] = nidx[i];
    }

    float s = sA + sB;
    float inv = 1.0f / s;  // deg >= 1 guaranteed
    float ox = (aAx + aBx) * inv;
    float oy = (aAy + aBy) * inv;

    if constexpr (F == 128) {
        float2 b2 = *(const float2*)&bias[2 * lane];
        ox += b2.x; oy += b2.y;
        if (RELU) { ox = fmaxf(ox, 0.f); oy = fmaxf(oy, 0.f); }
        *(float2*)&out[(size_t)n * 128 + 2 * lane] = make_float2(ox, oy);
    } else {
        ox += bias[lane];
        if (RELU) ox = fmaxf(ox, 0.f);
        out[(size_t)n * 64 + lane] = ox;
    }
}

// ---------------- host launch ----------------

static inline size_t alignup(size_t x) { return (x + 255) & ~(size_t)255; }

extern "C" void kernel_launch(void* const* d_in, const int* in_sizes, int n_in,
                              void* d_out, int out_size, void* d_ws, size_t ws_size,
                              hipStream_t stream) {
    const float* features = (const float*)d_in[0];
    const int* src = (const int*)d_in[1];
    const int* dst = (const int*)d_in[2];
    const float* W0 = (const float*)d_in[3];
    const float* al0 = (const float*)d_in[4];
    const float* ar0 = (const float*)d_in[5];
    const float* b0 = (const float*)d_in[6];
    const float* W1 = (const float*)d_in[7];
    const float* al1 = (const float*)d_in[8];
    const float* ar1 = (const float*)d_in[9];
    const float* b1 = (const float*)d_in[10];
    const float* W2 = (const float*)d_in[11];
    const float* al2 = (const float*)d_in[12];
    const float* ar2 = (const float*)d_in[13];
    const float* b2 = (const float*)d_in[14];
    float* out = (float*)d_out;

    const int N = in_sizes[0] / 128;  // 100000
    const int E = in_sizes[1];        // 1600000

    char* w = (char*)d_ws;
    int* cnt = (int*)w;        w += alignup((size_t)N * 4);
    int* rowptr = (int*)w;     w += alignup((size_t)(N + 1) * 4);
    int* nxt = (int*)w;        w += alignup((size_t)N * 4);
    int* bsum = (int*)w;       w += alignup(512 * 4);
    int* colx = (int*)w;       w += alignup((size_t)E * 4);
    float* ft = (float*)w;     w += alignup((size_t)N * 128 * 4);
    float* hbuf = (float*)w;   w += alignup((size_t)N * 128 * 4);
    float* el = (float*)w;     w += alignup((size_t)N * 4 * 4);
    float* er = (float*)w;     w += alignup((size_t)N * 4 * 4);

    const int nbE = (E + 255) / 256;
    const int nbN = (N + 255) / 256;

    // CSR build
    hipMemsetAsync(cnt, 0, (size_t)N * 4, stream);
    count_deg<<<nbE, 256, 0, stream>>>(dst, cnt, E);
    scan_block<<<nbN, 256, 0, stream>>>(cnt, rowptr, bsum, N);
    scan_partials<<<1, 512, 0, stream>>>(bsum, nbN);
    scan_add<<<nbN, 256, 0, stream>>>(rowptr, bsum, cnt, nxt, N);
    fill_csr<<<nbE, 256, 0, stream>>>(src, dst, nxt, colx, E);

    const int gGemm = (N + 127) / 128;
    const int gAgg = (N + 3) / 4;

    // Layer 0
    gemm_ft<128, 4><<<gGemm, 256, 0, stream>>>(features, W0, al0, ar0, ft, el, er, N);
    gat_aggregate<128, 4, true><<<gAgg, 256, 0, stream>>>(rowptr, colx, ft, el, er, b0, hbuf, N);

    // Layer 1
    gemm_ft<128, 4><<<gGemm, 256, 0, stream>>>(hbuf, W1, al1, ar1, ft, el, er, N);
    gat_aggregate<128, 4, true><<<gAgg, 256, 0, stream>>>(rowptr, colx, ft, el, er, b1, hbuf, N);

    // Layer 2
    gemm_ft<64, 1><<<gGemm, 256, 0, stream>>>(hbuf, W2, al2, ar2, ft, el, er, N);
    gat_aggregate<64, 1, false><<<gAgg, 256, 0, stream>>>(rowptr, colx, ft, el, er, b2, out, N);
}

// Round 5
// 648.235 us; speedup vs baseline: 1.7833x; 1.0115x over previous
//
#include <hip/hip_runtime.h>
#include <hip/hip_bf16.h>
#include <math.h>

// ---------------------------------------------------------------------------
// GAT (3-layer, DGL-style) on MI355X.
// CSR build (dst-sorted) -> per layer:
//   gemm_ft: K-tiled (BK=32) fp32 register GEMM, 128 x FOUT block tile,
//            ~33KB LDS -> 4 blocks/CU, fused el/er epilogue.
//   gat_aggregate: single-pass exp-weighted aggregation; TWO dst nodes per
//            wave (32 lanes each) so every instruction serves 2 edges;
//            8-wide batched gathers + index software-pipelining + masked
//            tail for max memory-level parallelism.
// ---------------------------------------------------------------------------

#define WAVE 64
constexpr int KDIM = 128;

// ---------------- CSR build ----------------

__global__ __launch_bounds__(256) void count_deg(const int* __restrict__ dst,
                                                 int* __restrict__ cnt, int E) {
    int e = blockIdx.x * 256 + threadIdx.x;
    if (e < E) atomicAdd(&cnt[dst[e]], 1);
}

__global__ __launch_bounds__(256) void scan_block(const int* __restrict__ cnt,
                                                  int* __restrict__ rowptr,
                                                  int* __restrict__ bsum, int n) {
    __shared__ int sh[256];
    int i = blockIdx.x * 256 + threadIdx.x;
    int v = (i < n) ? cnt[i] : 0;
    sh[threadIdx.x] = v;
    __syncthreads();
    for (int off = 1; off < 256; off <<= 1) {
        int t = (threadIdx.x >= off) ? sh[threadIdx.x - off] : 0;
        __syncthreads();
        sh[threadIdx.x] += t;
        __syncthreads();
    }
    if (i < n) rowptr[i + 1] = sh[threadIdx.x];
    if (threadIdx.x == 255) bsum[blockIdx.x] = sh[255];
}

__global__ __launch_bounds__(512) void scan_partials(int* __restrict__ bsum, int nb) {
    __shared__ int sh[512];
    int tid = threadIdx.x;
    int v = (tid < nb) ? bsum[tid] : 0;
    sh[tid] = v;
    __syncthreads();
    for (int off = 1; off < 512; off <<= 1) {
        int t = (tid >= off) ? sh[tid - off] : 0;
        __syncthreads();
        sh[tid] += t;
        __syncthreads();
    }
    if (tid < nb) bsum[tid] = sh[tid] - v;  // exclusive
}

__global__ __launch_bounds__(256) void scan_add(int* __restrict__ rowptr,
                                                const int* __restrict__ bsum,
                                                const int* __restrict__ cnt,
                                                int* __restrict__ nxt, int n) {
    int i = blockIdx.x * 256 + threadIdx.x;
    if (i < n) {
        int r = rowptr[i + 1] + bsum[blockIdx.x];
        rowptr[i + 1] = r;
        nxt[i] = r - cnt[i];
        if (i == 0) rowptr[0] = 0;
    }
}

__global__ __launch_bounds__(256) void fill_csr(const int* __restrict__ src,
                                                const int* __restrict__ dst,
                                                int* __restrict__ nxt,
                                                int* __restrict__ colx, int E) {
    int e = blockIdx.x * 256 + threadIdx.x;
    if (e < E) {
        int d = dst[e];
        int pos = atomicAdd(&nxt[d], 1);
        colx[pos] = src[e];
    }
}

// ---------------- GEMM + attention logits ----------------

template <int FOUT, int H>
__global__ __launch_bounds__(256, 4) void gemm_ft(
    const float* __restrict__ hin, const float* __restrict__ W,
    const float* __restrict__ al, const float* __restrict__ ar,
    float* __restrict__ ft, float* __restrict__ el, float* __restrict__ er,
    int nnodes) {
    constexpr int NODES = 128;
    constexpr int BK = 32;
    constexpr int LDH = 132;                  // padded (floats)
    constexpr int TN = (FOUT == 128) ? 8 : 4; // cols per thread

    __shared__ float ht[BK * LDH];   // 16.5 KB
    __shared__ float Ws[BK * FOUT];  // 16 KB (128) / 8 KB (64)

    const int tid = threadIdx.x;
    const int nb = blockIdx.x * NODES;
    const int tc = tid & 15, row = tid >> 4;

    float acc[8][TN];
#pragma unroll
    for (int m = 0; m < 8; ++m)
#pragma unroll
        for (int j = 0; j < TN; ++j) acc[m][j] = 0.f;

    const int nl = tid >> 3;          // 0..31
    const int kq = (tid & 7) * 4;     // 0,4,..,28

    for (int k0 = 0; k0 < KDIM; k0 += BK) {
#pragma unroll
        for (int it = 0; it < 4; ++it) {
            int nn = nl + it * 32;
            int n = nb + nn;
            float4 v = (n < nnodes)
                           ? *(const float4*)&hin[(size_t)n * KDIM + k0 + kq]
                           : make_float4(0.f, 0.f, 0.f, 0.f);
            ht[(kq + 0) * LDH + nn] = v.x;
            ht[(kq + 1) * LDH + nn] = v.y;
            ht[(kq + 2) * LDH + nn] = v.z;
            ht[(kq + 3) * LDH + nn] = v.w;
        }
        {
            const float4* Wg = (const float4*)&W[(size_t)k0 * FOUT];
#pragma unroll
            for (int it = 0; it < BK * FOUT / 1024; ++it)
                ((float4*)Ws)[tid + it * 256] = Wg[tid + it * 256];
        }
        __syncthreads();

#pragma unroll 4
        for (int kk = 0; kk < BK; ++kk) {
            float4 h0 = *(const float4*)&ht[kk * LDH + row * 4];
            float4 h1 = *(const float4*)&ht[kk * LDH + 64 + row * 4];
            float hv[8] = {h0.x, h0.y, h0.z, h0.w, h1.x, h1.y, h1.z, h1.w};
            float4 w0 = *(const float4*)&Ws[kk * FOUT + tc * 4];
            float wv[TN];
            wv[0] = w0.x; wv[1] = w0.y; wv[2] = w0.z; wv[3] = w0.w;
            if constexpr (FOUT == 128) {
                float4 w1 = *(const float4*)&Ws[kk * FOUT + 64 + tc * 4];
                wv[4] = w1.x; wv[5] = w1.y; wv[6] = w1.z; wv[7] = w1.w;
            }
#pragma unroll
            for (int m = 0; m < 8; ++m)
#pragma unroll
                for (int j = 0; j < TN; ++j)
                    acc[m][j] = fmaf(hv[m], wv[j], acc[m][j]);
        }
        __syncthreads();
    }

    float alv[TN], arv[TN];
#pragma unroll
    for (int j = 0; j < 4; ++j) {
        alv[j] = al[tc * 4 + j];
        arv[j] = ar[tc * 4 + j];
    }
    if constexpr (FOUT == 128) {
#pragma unroll
        for (int j = 0; j < 4; ++j) {
            alv[4 + j] = al[64 + tc * 4 + j];
            arv[4 + j] = ar[64 + tc * 4 + j];
        }
    }

#pragma unroll
    for (int m = 0; m < 8; ++m) {
        const int r = (m < 4) ? (row * 4 + m) : (64 + row * 4 + m - 4);
        const int n = nb + r;
        const bool valid = n < nnodes;

        float pl0 = 0.f, pr0 = 0.f, pl1 = 0.f, pr1 = 0.f;
#pragma unroll
        for (int j = 0; j < 4; ++j) {
            pl0 = fmaf(acc[m][j], alv[j], pl0);
            pr0 = fmaf(acc[m][j], arv[j], pr0);
        }
        if constexpr (FOUT == 128) {
#pragma unroll
            for (int j = 0; j < 4; ++j) {
                pl1 = fmaf(acc[m][4 + j], alv[4 + j], pl1);
                pr1 = fmaf(acc[m][4 + j], arv[4 + j], pr1);
            }
        }

        if constexpr (H == 4) {
#pragma unroll
            for (int msk = 1; msk < 8; msk <<= 1) {
                pl0 += __shfl_xor(pl0, msk);
                pr0 += __shfl_xor(pr0, msk);
                pl1 += __shfl_xor(pl1, msk);
                pr1 += __shfl_xor(pr1, msk);
            }
            if (valid && (tc == 0 || tc == 8)) {
                int hbase = (tc == 0) ? 0 : 1;
                el[(size_t)n * 4 + hbase] = pl0;
                er[(size_t)n * 4 + hbase] = pr0;
                el[(size_t)n * 4 + hbase + 2] = pl1;
                er[(size_t)n * 4 + hbase + 2] = pr1;
            }
        } else {
#pragma unroll
            for (int msk = 1; msk < 16; msk <<= 1) {
                pl0 += __shfl_xor(pl0, msk);
                pr0 += __shfl_xor(pr0, msk);
            }
            if (valid && tc == 0) {
                el[n] = pl0;
                er[n] = pr0;
            }
        }

        if (valid) {
            *(float4*)&ft[(size_t)n * FOUT + tc * 4] =
                make_float4(acc[m][0], acc[m][1], acc[m][2], acc[m][3]);
            if constexpr (FOUT == 128)
                *(float4*)&ft[(size_t)n * FOUT + 64 + tc * 4] =
                    make_float4(acc[m][4], acc[m][5], acc[m][6], acc[m][7]);
        }
    }
}

// ---------------- Edge-softmax aggregation ----------------
// TWO dst nodes per wave: lanes 0-31 -> node A, lanes 32-63 -> node B.
// Each lane owns CPL = F/32 columns. Per iteration: 8 batched ft gathers
// (long latency first), 8 el gathers, prefetch next 8 indices, compute.
// Tail masked via idx=-1 -> p=0. Loop count = max(degA,degB) (wave-uniform).

template <int F, int H, bool RELU>
__global__ __launch_bounds__(256) void gat_aggregate(
    const int* __restrict__ rowptr, const int* __restrict__ colx,
    const float* __restrict__ ft, const float* __restrict__ el,
    const float* __restrict__ er, const float* __restrict__ bias,
    float* __restrict__ out, int nnodes) {
    constexpr int UN = 8;
    constexpr int CPL = F / 32;  // cols per lane: 4 (F=128) or 2 (F=64)
    const int tid = threadIdx.x, wv = tid >> 6, lane = tid & 63;
    const int grp = lane >> 5, sub = lane & 31;
    const int n = blockIdx.x * 8 + wv * 2 + grp;
    const bool valid = n < nnodes;
    const int nn = valid ? n : 0;

    const int start = rowptr[nn];
    const int end = valid ? rowptr[nn + 1] : start;  // deg 0 if invalid
    const int deg = end - start;
    const int odeg = __shfl_xor(deg, 32);
    const int mdeg = max(deg, odeg);
    const int nit = (mdeg + UN - 1) / UN;

    // head for this lane's columns (F=128: cols 4*sub.. -> head=sub>>3)
    const int head = (H == 4) ? (sub >> 3) : 0;
    const float er_s = (H == 4) ? er[(size_t)nn * 4 + head] : er[nn];

    float sA = 0.f, sB = 0.f;
    float aA[CPL], aB[CPL];
#pragma unroll
    for (int c = 0; c < CPL; ++c) { aA[c] = 0.f; aB[c] = 0.f; }

    int idx[UN];
#pragma unroll
    for (int i = 0; i < UN; ++i) {
        int ee = start + i;
        idx[i] = (ee < end) ? colx[ee] : -1;
    }

    for (int it = 0; it < nit; ++it) {
        // 1) long-latency ft gathers first (8 independent, all in flight)
        float fx[UN][CPL];
#pragma unroll
        for (int i = 0; i < UN; ++i) {
            int sn = (idx[i] < 0) ? 0 : idx[i];
            if constexpr (CPL == 4) {
                float4 v = *(const float4*)&ft[(size_t)sn * F + sub * 4];
                fx[i][0] = v.x; fx[i][1] = v.y; fx[i][2] = v.z; fx[i][3] = v.w;
            } else {
                float2 v = *(const float2*)&ft[(size_t)sn * F + sub * 2];
                fx[i][0] = v.x; fx[i][1] = v.y;
            }
        }
        // 2) el gathers
        float xl[UN];
#pragma unroll
        for (int i = 0; i < UN; ++i) {
            int sn = (idx[i] < 0) ? 0 : idx[i];
            xl[i] = (H == 4) ? el[(size_t)sn * 4 + head] : el[sn];
        }
        // 3) software-pipeline: prefetch next batch of indices
        int nidx[UN];
        {
            int base2 = start + (it + 1) * UN;
#pragma unroll
            for (int i = 0; i < UN; ++i) {
                int ee = base2 + i;
                nidx[i] = (ee < end) ? colx[ee] : -1;
            }
        }
        // 4) compute
#pragma unroll
        for (int i = 0; i < UN; ++i) {
            float x = xl[i] + er_s;
            x = fmaxf(x, 0.2f * x);  // leaky_relu
            float p = __expf(x);
            p = (idx[i] >= 0) ? p : 0.f;
            if (i & 1) {
                sB += p;
#pragma unroll
                for (int c = 0; c < CPL; ++c) aB[c] = fmaf(p, fx[i][c], aB[c]);
            } else {
                sA += p;
#pragma unroll
                for (int c = 0; c < CPL; ++c) aA[c] = fmaf(p, fx[i][c], aA[c]);
            }
        }
#pragma unroll
        for (int i = 0; i < UN; ++i) idx[i] = nidx[i];
    }

    if (!valid) return;
    float s = sA + sB;
    float inv = 1.0f / s;  // deg >= 1 guaranteed for valid nodes
    float o[CPL];
#pragma unroll
    for (int c = 0; c < CPL; ++c) {
        o[c] = (aA[c] + aB[c]) * inv + bias[sub * CPL + c];
        if (RELU) o[c] = fmaxf(o[c], 0.f);
    }
    if constexpr (CPL == 4) {
        *(float4*)&out[(size_t)n * F + sub * 4] =
            make_float4(o[0], o[1], o[2], o[3]);
    } else {
        *(float2*)&out[(size_t)n * F + sub * 2] = make_float2(o[0], o[1]);
    }
}

// ---------------- host launch ----------------

static inline size_t alignup(size_t x) { return (x + 255) & ~(size_t)255; }

extern "C" void kernel_launch(void* const* d_in, const int* in_sizes, int n_in,
                              void* d_out, int out_size, void* d_ws, size_t ws_size,
                              hipStream_t stream) {
    const float* features = (const float*)d_in[0];
    const int* src = (const int*)d_in[1];
    const int* dst = (const int*)d_in[2];
    const float* W0 = (const float*)d_in[3];
    const float* al0 = (const float*)d_in[4];
    const float* ar0 = (const float*)d_in[5];
    const float* b0 = (const float*)d_in[6];
    const float* W1 = (const float*)d_in[7];
    const float* al1 = (const float*)d_in[8];
    const float* ar1 = (const float*)d_in[9];
    const float* b1 = (const float*)d_in[10];
    const float* W2 = (const float*)d_in[11];
    const float* al2 = (const float*)d_in[12];
    const float* ar2 = (const float*)d_in[13];
    const float* b2 = (const float*)d_in[14];
    float* out = (float*)d_out;

    const int N = in_sizes[0] / 128;  // 100000
    const int E = in_sizes[1];        // 1600000

    char* w = (char*)d_ws;
    int* cnt = (int*)w;        w += alignup((size_t)N * 4);
    int* rowptr = (int*)w;     w += alignup((size_t)(N + 1) * 4);
    int* nxt = (int*)w;        w += alignup((size_t)N * 4);
    int* bsum = (int*)w;       w += alignup(512 * 4);
    int* colx = (int*)w;       w += alignup((size_t)E * 4);
    float* ft = (float*)w;     w += alignup((size_t)N * 128 * 4);
    float* hbuf = (float*)w;   w += alignup((size_t)N * 128 * 4);
    float* el = (float*)w;     w += alignup((size_t)N * 4 * 4);
    float* er = (float*)w;     w += alignup((size_t)N * 4 * 4);

    const int nbE = (E + 255) / 256;
    const int nbN = (N + 255) / 256;

    // CSR build
    hipMemsetAsync(cnt, 0, (size_t)N * 4, stream);
    count_deg<<<nbE, 256, 0, stream>>>(dst, cnt, E);
    scan_block<<<nbN, 256, 0, stream>>>(cnt, rowptr, bsum, N);
    scan_partials<<<1, 512, 0, stream>>>(bsum, nbN);
    scan_add<<<nbN, 256, 0, stream>>>(rowptr, bsum, cnt, nxt, N);
    fill_csr<<<nbE, 256, 0, stream>>>(src, dst, nxt, colx, E);

    const int gGemm = (N + 127) / 128;
    const int gAgg = (N + 7) / 8;  // 2 nodes per wave, 4 waves per block

    // Layer 0
    gemm_ft<128, 4><<<gGemm, 256, 0, stream>>>(features, W0, al0, ar0, ft, el, er, N);
    gat_aggregate<128, 4, true><<<gAgg, 256, 0, stream>>>(rowptr, colx, ft, el, er, b0, hbuf, N);

    // Layer 1
    gemm_ft<128, 4><<<gGemm, 256, 0, stream>>>(hbuf, W1, al1, ar1, ft, el, er, N);
    gat_aggregate<128, 4, true><<<gAgg, 256, 0, stream>>>(rowptr, colx, ft, el, er, b1, hbuf, N);

    // Layer 2
    gemm_ft<64, 1><<<gGemm, 256, 0, stream>>>(hbuf, W2, al2, ar2, ft, el, er, N);
    gat_aggregate<64, 1, false><<<gAgg, 256, 0, stream>>>(rowptr, colx, ft, el, er, b2, out, N);
}